// Round 3
// baseline (480.204 us; speedup 1.0000x reference)
//
#include <hip/hip_runtime.h>

// PWC-Net 9x9 correlation, direct-register + explicit software pipeline.
// out[b, dy*9+dx, y, x] = (1/C) * sum_c F[b,c,y,x] * S[b,c,y+dy-4,x+dx-4]
//
// R2 post-mortem: launch_bounds(192,4) capped VGPRs at 128; compiler
// serialized the 6 loads per channel (load->waitcnt->use x6, ~2800 cyc/iter,
// VALUBusy 15%). Fix: depth-1 prefetch (load c+1 while FMA c) under
// launch_bounds(192,3) (~168 VGPR cap; we need ~140). Exposed latency per
// iter drops from ~6L to max(0, L-144), covered by ~3 waves/SIMD.

namespace {
constexpr int kC = 128;
constexpr int kH = 112;
constexpr int kW = 192;
constexpr int kD = 4;            // max displacement
constexpr int kKD = 9;           // 2*kD+1
constexpr int kHW = kH * kW;     // 21504
constexpr long long kCHW = (long long)kC * kHW;

constexpr int PX = 8;            // pixels per thread along x
constexpr int XG = kW / PX;      // 24 x-groups
constexpr int YT = 8;            // rows per block
constexpr int NT = XG * YT;      // 192 threads = 3 waves
}  // namespace

__device__ __attribute__((aligned(16))) float g_zeros[4] = {0.f, 0.f, 0.f, 0.f};

__global__ __launch_bounds__(NT, 3)
void corr81_kernel(const float* __restrict__ first,
                   const float* __restrict__ second,
                   float* __restrict__ out) {
  const int g = blockIdx.x;
  const int b = g & 7;             // batch -> XCD slab
  const int i = g >> 3;
  const int dy = i % kKD;          // dy innermost: L2 sliding window
  const int y0 = (i / kKD) * YT;

  const int tid = threadIdx.x;
  const int xg = tid % XG;
  const int yl = tid / XG;
  const int px0 = xg * PX;
  const int y = y0 + yl;
  const int ys = y + dy - kD;      // second row for this dy (may be OOB)

  float acc[PX][kKD];
#pragma unroll
  for (int p = 0; p < PX; ++p)
#pragma unroll
    for (int d = 0; d < kKD; ++d) acc[p][d] = 0.0f;

  if ((unsigned)ys < (unsigned)kH) {
    const bool left = (xg == 0);          // window [-4,0) is zero padding
    const bool right = (xg == XG - 1);    // window [192,196) is zero padding

    const float* fp = first + (long long)b * kCHW + (long long)y * kW + px0;
    const float* sp = second + (long long)b * kCHW + (long long)ys * kW + px0;
    const float* pw0 = left ? g_zeros : (sp - 4);   // window floats [0,4)
    const float* pw3 = right ? g_zeros : (sp + 8);  // window floats [12,16)
    const long long st0 = left ? 0 : kHW;
    const long long st3 = right ? 0 : kHW;

    // prologue: load channel 0
    float4 f0 = *(const float4*)(fp);
    float4 f1 = *(const float4*)(fp + 4);
    float4 w0 = *(const float4*)(pw0);
    float4 w1 = *(const float4*)(sp);       // window floats [4,8)
    float4 w2 = *(const float4*)(sp + 4);   // window floats [8,12)
    float4 w3 = *(const float4*)(pw3);

    for (int c = 1; c < kC; ++c) {
      // issue channel c's loads before consuming channel c-1's data
      fp += kHW;
      sp += kHW;
      pw0 += st0;
      pw3 += st3;
      const float4 nf0 = *(const float4*)(fp);
      const float4 nf1 = *(const float4*)(fp + 4);
      const float4 nw0 = *(const float4*)(pw0);
      const float4 nw1 = *(const float4*)(sp);
      const float4 nw2 = *(const float4*)(sp + 4);
      const float4 nw3 = *(const float4*)(pw3);

      {
        const float fa[PX] = {f0.x, f0.y, f0.z, f0.w, f1.x, f1.y, f1.z, f1.w};
        const float sw[16] = {w0.x, w0.y, w0.z, w0.w, w1.x, w1.y, w1.z, w1.w,
                              w2.x, w2.y, w2.z, w2.w, w3.x, w3.y, w3.z, w3.w};
#pragma unroll
        for (int p = 0; p < PX; ++p)
#pragma unroll
          for (int d = 0; d < kKD; ++d)
            acc[p][d] = fmaf(fa[p], sw[p + d], acc[p][d]);
      }

      f0 = nf0; f1 = nf1; w0 = nw0; w1 = nw1; w2 = nw2; w3 = nw3;
    }

    // epilogue FMA for the last channel
    {
      const float fa[PX] = {f0.x, f0.y, f0.z, f0.w, f1.x, f1.y, f1.z, f1.w};
      const float sw[16] = {w0.x, w0.y, w0.z, w0.w, w1.x, w1.y, w1.z, w1.w,
                            w2.x, w2.y, w2.z, w2.w, w3.x, w3.y, w3.z, w3.w};
#pragma unroll
      for (int p = 0; p < PX; ++p)
#pragma unroll
        for (int d = 0; d < kKD; ++d)
          acc[p][d] = fmaf(fa[p], sw[p + d], acc[p][d]);
    }
  }

  // epilogue: 9 dx channels x 8 px, coalesced dwordx4 stores (zeros if ys OOB)
  const float scale = 1.0f / (float)kC;
  float* obase = out + ((long long)b * 81 + (long long)dy * kKD) * kHW +
                 (long long)y * kW + px0;
#pragma unroll
  for (int d = 0; d < kKD; ++d) {
    float4 o0 = make_float4(acc[0][d] * scale, acc[1][d] * scale,
                            acc[2][d] * scale, acc[3][d] * scale);
    float4 o1 = make_float4(acc[4][d] * scale, acc[5][d] * scale,
                            acc[6][d] * scale, acc[7][d] * scale);
    float* op = obase + (long long)d * kHW;
    *(float4*)op = o0;
    *(float4*)(op + 4) = o1;
  }
}

extern "C" void kernel_launch(void* const* d_in, const int* in_sizes, int n_in,
                              void* d_out, int out_size, void* d_ws, size_t ws_size,
                              hipStream_t stream) {
  const float* first = (const float*)d_in[0];
  const float* second = (const float*)d_in[1];
  float* out = (float*)d_out;

  const int grid = 8 * (kH / YT) * kKD;  // 8 * 14 * 9 = 1008 blocks
  corr81_kernel<<<grid, NT, 0, stream>>>(first, second, out);
}

// Round 4
// 334.012 us; speedup vs baseline: 1.4377x; 1.4377x over previous
//
#include <hip/hip_runtime.h>

// PWC-Net 9x9 correlation via bf16 MFMA (v_mfma_f32_16x16x32_bf16).
// out[b,(dy)*9+(dx), y, x] = (1/128) sum_c F[b,c,y,x] * S[b,c,y+dy-4,x+dx-4]
//
// Banded-matmul formulation: per (y, dy): D[x, xs] = sum_c F[c,x]*S[c,ys,xs],
// x in [x0,x0+16), xs in [x0-4,x0+28) (N=32, two 16-wide tiles), K=C=128 in
// 4 chunks of 32. dx = xs-x in [-4,4] extracted from the dense tile.
// Block: (b, 8 y-rows, 16 x) = 384 thr / 6 waves; wave = (ygrp 0..1, dygrp 0..2)
// owns 4y x 3dy = 12 products -> 24 C-tiles = 96 acc regs (AGPR-friendly).
// LDS: A[y][x][k] and B[ys][xs][k], K-major 32-ch rows (64 B stride ->
// uniform banks for ds_*_b128). Staging: thread gathers 8 channel-strided
// dwords (lanes x-coalesced), packs to bf16 (+0x8000 RN), one ds_write_b128.

typedef __attribute__((ext_vector_type(8))) short bf16x8;
typedef __attribute__((ext_vector_type(4))) float f32x4;

namespace {
constexpr int kC = 128, kH = 112, kW = 192;
constexpr int kHW = kH * kW;                    // 21504
constexpr long long kCHW = (long long)kC * kHW;
constexpr int YT = 8;                           // output rows per block
constexpr int XT = 16;                          // x per block (M)
constexpr int NS = 32;                          // staged xs (N)
constexpr int YS = 16;                          // staged ys rows (y0-4..y0+11)
constexpr int KC = 32;                          // channels per LDS chunk
constexpr int NT = 384;                         // 6 waves
constexpr int A_YSTRIDE = XT * KC * 2;          // 1024 B per y row-block
constexpr int B_YSTRIDE = NS * KC * 2;          // 2048 B per ys row-block
constexpr int B_OFF = YT * A_YSTRIDE;           // 8192
constexpr int LDS_BYTES = B_OFF + YS * B_YSTRIDE;  // 40960
constexpr int A_SLOTS = YT * XT * (KC / 8);     // 512
constexpr int B_SLOTS = YS * NS * (KC / 8);     // 2048
}  // namespace

__device__ __forceinline__ unsigned pack2_bf16(float a, float b) {
  unsigned ua = __float_as_uint(a) + 0x8000u;   // round-to-nearest (ties away)
  unsigned ub = __float_as_uint(b) + 0x8000u;
  return (ua >> 16) | (ub & 0xffff0000u);
}

__global__ __launch_bounds__(NT, 3)
void corr81_mfma(const float* __restrict__ first,
                 const float* __restrict__ second,
                 float* __restrict__ out) {
  __shared__ uint4 lds4[LDS_BYTES / 16];
  unsigned char* lds = (unsigned char*)lds4;

  const int g = blockIdx.x;
  const int b = g & 7;                  // batch -> XCD slab
  const int i = g >> 3;
  const int xt = i % (kW / XT);         // 12 x-tiles (innermost: S-row L2 reuse)
  const int yt = i / (kW / XT);         // 14 y-tiles
  const int x0 = xt * XT, y0 = yt * YT;

  const int tid = threadIdx.x;
  const int lane = tid & 63;
  const int wv = tid >> 6;              // 0..5
  const int dy_w = (wv % 3) * 3;        // dy_idx group base: 0,3,6
  const int y_w = (wv / 3) * 4;         // y group base: 0,4
  const int col = lane & 15;
  const int q = lane >> 4;

  f32x4 acc[4][3][2];
#pragma unroll
  for (int yy = 0; yy < 4; ++yy)
#pragma unroll
    for (int dd = 0; dd < 3; ++dd)
#pragma unroll
      for (int nh = 0; nh < 2; ++nh) acc[yy][dd][nh] = (f32x4){0.f, 0.f, 0.f, 0.f};

  const float* fb = first + (long long)b * kCHW;
  const float* sb = second + (long long)b * kCHW;

  for (int ck = 0; ck < kC / KC; ++ck) {
    const int c0 = ck * KC;
    __syncthreads();  // previous chunk's frag reads complete

    // ---- stage chunk: global fp32 -> bf16 -> LDS K-major rows ----
    for (int s = tid; s < A_SLOTS + B_SLOTS; s += NT) {
      if (s < A_SLOTS) {
        const int kg = s & 3, xl = (s >> 2) & 15, yl = s >> 6;
        const float* p = fb + (long long)(c0 + kg * 8) * kHW +
                         (y0 + yl) * kW + (x0 + xl);
        uint4 w;
        w.x = pack2_bf16(p[0], p[kHW]);
        w.y = pack2_bf16(p[2 * kHW], p[3 * kHW]);
        w.z = pack2_bf16(p[4 * kHW], p[5 * kHW]);
        w.w = pack2_bf16(p[6 * kHW], p[7 * kHW]);
        *(uint4*)(lds + yl * A_YSTRIDE + xl * (KC * 2) + kg * 16) = w;
      } else {
        const int t = s - A_SLOTS;
        const int kg = t & 3, n = (t >> 2) & 31, ys = t >> 7;
        const int ysg = y0 + ys - 4;       // global second row
        const int xsg = x0 + n - 4;        // global second col
        uint4 w = make_uint4(0u, 0u, 0u, 0u);
        if ((unsigned)ysg < (unsigned)kH && (unsigned)xsg < (unsigned)kW) {
          const float* p = sb + (long long)(c0 + kg * 8) * kHW +
                           ysg * kW + xsg;
          w.x = pack2_bf16(p[0], p[kHW]);
          w.y = pack2_bf16(p[2 * kHW], p[3 * kHW]);
          w.z = pack2_bf16(p[4 * kHW], p[5 * kHW]);
          w.w = pack2_bf16(p[6 * kHW], p[7 * kHW]);
        }
        *(uint4*)(lds + B_OFF + ys * B_YSTRIDE + n * (KC * 2) + kg * 16) = w;
      }
    }
    __syncthreads();

    // ---- fragments + 24 mfma (one K-step of 32 per chunk) ----
    bf16x8 aF[4];
#pragma unroll
    for (int yy = 0; yy < 4; ++yy)
      aF[yy] = *(const bf16x8*)(lds + (y_w + yy) * A_YSTRIDE + col * (KC * 2) +
                                q * 16);
    const int sbase = y_w + dy_w;  // B row for (yy,dd) is sbase + yy + dd
#pragma unroll
    for (int nh = 0; nh < 2; ++nh) {
      bf16x8 bF[6];
#pragma unroll
      for (int si = 0; si < 6; ++si)
        bF[si] = *(const bf16x8*)(lds + B_OFF + (sbase + si) * B_YSTRIDE +
                                  (nh * 16 + col) * (KC * 2) + q * 16);
#pragma unroll
      for (int yy = 0; yy < 4; ++yy)
#pragma unroll
        for (int dd = 0; dd < 3; ++dd)
          acc[yy][dd][nh] = __builtin_amdgcn_mfma_f32_16x16x32_bf16(
              aF[yy], bF[yy + dd], acc[yy][dd][nh], 0, 0, 0);
    }
  }

  // ---- epilogue: D[m=x][n=xs]; lane: col=n&15, rows m=q*4+r; dx=xs-x ----
  const float scale = 1.f / 128.f;
#pragma unroll
  for (int nh = 0; nh < 2; ++nh)
#pragma unroll
    for (int r = 0; r < 4; ++r) {
      const int xloc = q * 4 + r;
      const int d = nh * 16 + col - xloc;  // dx index = dx+4
      if ((unsigned)d <= 8u) {
#pragma unroll
        for (int yy = 0; yy < 4; ++yy)
#pragma unroll
          for (int dd = 0; dd < 3; ++dd) {
            const int ch = (dy_w + dd) * 9 + d;
            const long long o =
                (((long long)b * 81 + ch) * kH + (y0 + y_w + yy)) *
                    (long long)kW +
                (x0 + xloc);
            out[o] = acc[yy][dd][nh][r] * scale;
          }
      }
    }
}

extern "C" void kernel_launch(void* const* d_in, const int* in_sizes, int n_in,
                              void* d_out, int out_size, void* d_ws, size_t ws_size,
                              hipStream_t stream) {
  const float* first = (const float*)d_in[0];
  const float* second = (const float*)d_in[1];
  float* out = (float*)d_out;

  const int grid = 8 * (kH / YT) * (kW / XT);  // 8*14*12 = 1344
  corr81_mfma<<<grid, NT, 0, stream>>>(first, second, out);
}